// Round 5
// baseline (231.931 us; speedup 1.0000x reference)
//
#include <hip/hip_runtime.h>
#include <hip/hip_bf16.h>
#include <stdint.h>

typedef unsigned short u16;
typedef unsigned int   u32;
typedef __attribute__((ext_vector_type(8))) short bf16x8;
typedef __attribute__((ext_vector_type(8))) unsigned short u16x8;
typedef __attribute__((ext_vector_type(4))) float f32x4;
typedef __attribute__((ext_vector_type(4))) _Float16 f16x4;

#define SCALE 0.08838834764831845f
// SCALE * log2(e): scores scaled directly into exp2 domain
#define SC2 0.1275174475f

// PV matrix op: 16x16x16 f16 (K=16 matches the per-wave key slice)
#if __has_builtin(__builtin_amdgcn_mfma_f32_16x16x16_f16)
#define MFMA16(A, B, C) __builtin_amdgcn_mfma_f32_16x16x16_f16(A, B, C, 0, 0, 0)
#else
#define MFMA16(A, B, C) __builtin_amdgcn_mfma_f32_16x16x16f16(A, B, C, 0, 0, 0)
#endif
#define MFMA32(A, B, C) __builtin_amdgcn_mfma_f32_16x16x32_bf16(A, B, C, 0, 0, 0)

__device__ __forceinline__ float bf2f(u16 u) {
    union { u32 i; float f; } t; t.i = ((u32)u) << 16; return t.f;
}
__device__ __forceinline__ u16 f2bf(float f) {
    union { u32 i; float f; } t; t.f = f;
    u32 b = t.i;
    return (u16)((b + 0x7fffu + ((b >> 16) & 1u)) >> 16);
}
__device__ __forceinline__ u16 f2h(float f) {
    union { _Float16 h; u16 u; } c; c.h = (_Float16)f; return c.u;
}

// async global->LDS, 16B per lane, linear LDS dest (wave-uniform base + lane*16)
__device__ __forceinline__ void gload16(const u16* g, u16* l) {
    __builtin_amdgcn_global_load_lds(
        (const __attribute__((address_space(1))) void*)g,
        (__attribute__((address_space(3))) void*)l, 16, 0, 0);
}

// ============================================================
// Kernel 0: GroupNorm stats -> per-channel affine tables.
// ============================================================
__global__ __launch_bounds__(256) void stats_kernel(
    const float* __restrict__ x, const float* __restrict__ gw,
    const float* __restrict__ gb, float* __restrict__ gp, float* __restrict__ bp)
{
    int b = blockIdx.x >> 5, g = blockIdx.x & 31;
    long base = ((long)(b * 128 + g * 4)) << 12;
    const float4* x4 = (const float4*)(x + base);

    float s = 0.f, ss = 0.f;
    for (int i = threadIdx.x; i < 4096; i += 256) {
        float4 v = x4[i];
        s  += v.x + v.y + v.z + v.w;
        ss += v.x * v.x + v.y * v.y + v.z * v.z + v.w * v.w;
    }
    #pragma unroll
    for (int off = 32; off > 0; off >>= 1) {
        s  += __shfl_xor(s,  off);
        ss += __shfl_xor(ss, off);
    }
    __shared__ float red[8];
    int wid = threadIdx.x >> 6;
    if ((threadIdx.x & 63) == 0) { red[wid * 2] = s; red[wid * 2 + 1] = ss; }
    __syncthreads();
    s  = red[0] + red[2] + red[4] + red[6];
    ss = red[1] + red[3] + red[5] + red[7];

    float mean = s * (1.f / 16384.f);
    float var  = ss * (1.f / 16384.f) - mean * mean;
    float rs   = rsqrtf(var + 1e-5f);

    if (threadIdx.x < 4) {
        int c = g * 4 + threadIdx.x;
        float gamma = gw[c] * rs;
        gp[b * 128 + c] = gamma;
        bp[b * 128 + c] = gb[c] - mean * gamma;
    }
}

// ============================================================
// Kernel 0b: w fp32 -> bf16
// ============================================================
__global__ __launch_bounds__(256) void wconv_kernel(
    const float* __restrict__ w, u16* __restrict__ wbf)
{
    int idx = (blockIdx.x * 256 + threadIdx.x) * 4;
    float4 v = *(const float4*)&w[idx];
    ushort4 o = { f2bf(v.x), f2bf(v.y), f2bf(v.z), f2bf(v.w) };
    *(ushort4*)&wbf[idx] = o;
}

// ============================================================
// Kernel 1: apply GN + transpose -> hn [b][s][c] bf16.
// ============================================================
__global__ __launch_bounds__(256) void apply_kernel(
    const float* __restrict__ x, const float* __restrict__ gp,
    const float* __restrict__ bp, u16* __restrict__ hn)
{
    __shared__ u16 ldsT[128 * 128];   // 32 KB
    __shared__ float gpl[128], bpl[128];
    int b = blockIdx.x >> 5, st = blockIdx.x & 31;
    int s0 = st << 7;
    int t = threadIdx.x;
    if (t < 128) { gpl[t] = gp[b * 128 + t]; bpl[t] = bp[b * 128 + t]; }
    __syncthreads();

    const float* xb = x + ((long)b << 19);
    int sl = t & 127, chalf = t >> 7;
    #pragma unroll
    for (int c8 = 0; c8 < 8; ++c8) {
        int CH = chalf * 8 + c8;
        u16 tmp[8];
        #pragma unroll
        for (int j = 0; j < 8; ++j) {
            int c = CH * 8 + j;
            float v = xb[((long)c << 12) + s0 + sl];
            tmp[j] = f2bf(v * gpl[c] + bpl[c]);
        }
        *(u16x8*)&ldsT[sl * 128 + ((CH ^ (sl & 15)) << 3)] = *(u16x8*)tmp;
    }
    __syncthreads();

    u16* hnb = hn + ((long)b << 19);
    int s = t >> 1, h = t & 1;
    #pragma unroll
    for (int i = 0; i < 8; ++i) {
        int CH = h * 8 + i;
        u16x8 v = *(u16x8*)&ldsT[s * 128 + ((CH ^ (s & 15)) << 3)];
        *(u16x8*)&hnb[(long)(s0 + s) * 128 + CH * 8] = v;
    }
}

// ============================================================
// Kernel 2: QKV projection via MFMA. Q,K -> bf16 [b][s][128];
// V -> fp16 [b][c][s] (fp16 is the PV A-operand dtype now).
// ============================================================
__global__ __launch_bounds__(256) void qkvm_kernel(
    const u16* __restrict__ hn, const u16* __restrict__ wbf,
    const float* __restrict__ bias,
    u16* __restrict__ Qt, u16* __restrict__ Kt, u16* __restrict__ Vv)
{
    __shared__ u16 ldsH[64 * 128];   // 16 KB
    int tid = threadIdx.x, lane = tid & 63, wv = tid >> 6;
    int g = lane >> 4, t = lane & 15;
    int b = blockIdx.x >> 6, stile = blockIdx.x & 63;
    int s0 = stile << 6;

    const u16* hnb = hn + ((long)b << 19);
    #pragma unroll
    for (int i = 0; i < 4; ++i) {
        int seg = wv * 4 + i;
        int n = seg * 64 + lane;
        int s = n >> 4, SL = n & 15;
        int gch = SL ^ (s & 15);
        gload16(hnb + (long)(s0 + s) * 128 + gch * 8, &ldsH[seg * 512]);
    }
    __syncthreads();

    bf16x8 hf[4];
    int slq = (wv << 4) + t;
    #pragma unroll
    for (int ks = 0; ks < 4; ++ks)
        hf[ks] = *(const bf16x8*)&ldsH[slq * 128 + ((((ks << 2) + g) ^ t) << 3)];

    u16* Qtb = Qt + ((long)b << 19);
    u16* Ktb = Kt + ((long)b << 19);
    u16* Vb  = Vv + ((long)b << 19);
    int srow = s0 + (wv << 4) + (g << 2);

    #pragma unroll
    for (int ot = 0; ot < 8; ++ot) {
        bf16x8 wf[4];
        #pragma unroll
        for (int ks = 0; ks < 4; ++ks)
            wf[ks] = *(const bf16x8*)&wbf[(ot * 16 + t) * 128 + ks * 32 + g * 8];
        float bv = bias[ot * 16 + t];
        f32x4 acc = (f32x4){bv, bv, bv, bv};
        #pragma unroll
        for (int ks = 0; ks < 4; ++ks)
            acc = MFMA32(hf[ks], wf[ks], acc);
        #pragma unroll
        for (int r = 0; r < 4; ++r)
            Qtb[(long)(srow + r) * 128 + ot * 16 + t] = f2bf(acc[r]);
    }
    #pragma unroll
    for (int ot = 8; ot < 16; ++ot) {
        bf16x8 wf[4];
        #pragma unroll
        for (int ks = 0; ks < 4; ++ks)
            wf[ks] = *(const bf16x8*)&wbf[(ot * 16 + t) * 128 + ks * 32 + g * 8];
        float bv = bias[ot * 16 + t];
        f32x4 acc = (f32x4){bv, bv, bv, bv};
        #pragma unroll
        for (int ks = 0; ks < 4; ++ks)
            acc = MFMA32(hf[ks], wf[ks], acc);
        #pragma unroll
        for (int r = 0; r < 4; ++r)
            Ktb[(long)(srow + r) * 128 + (ot - 8) * 16 + t] = f2bf(acc[r]);
    }
    #pragma unroll
    for (int ot = 16; ot < 24; ++ot) {
        bf16x8 wf[4];
        #pragma unroll
        for (int ks = 0; ks < 4; ++ks)
            wf[ks] = *(const bf16x8*)&wbf[(ot * 16 + t) * 128 + ks * 32 + g * 8];
        float4 b4 = *(const float4*)&bias[ot * 16 + (g << 2)];
        f32x4 acc = (f32x4){b4.x, b4.y, b4.z, b4.w};
        #pragma unroll
        for (int ks = 0; ks < 4; ++ks)
            acc = MFMA32(wf[ks], hf[ks], acc);
        #pragma unroll
        for (int r = 0; r < 4; ++r) {
            int cv = (ot - 16) * 16 + (g << 2) + r;
            Vb[((long)cv << 12) + s0 + (wv << 4) + t] = f2h(acc[r]);
        }
    }
}

// ============================================================
// Kernel 3: MFMA flash attention + final x*a multiply.
// Round-5 structure: each of 4 waves owns a 16-KEY slice of every
// 64-key tile and ALL 64 q-rows (4 qsets). K-frag b128 reads reused
// 4x; PV uses 16x16x16 fp16 whose B-frag layout == QK S^T D-layout
// (zero shuffles). Per-wave partial (m,l,O) merged once at the end.
// ============================================================
__global__ __launch_bounds__(256, 2) void attn_kernel(
    const u16* __restrict__ Qt, const u16* __restrict__ Kt,
    const u16* __restrict__ Vv, const float* __restrict__ x,
    float* __restrict__ out)
{
    __shared__ u16 ldsK[2][8192];   // [64 s][16 ch16][8 u16], src-swizzled ch^(s&7)
    __shared__ u16 ldsV[2][8192];   // [128 c][16 ch8][4 u16], src-swizzled ch8^(c&14)

    int tid = threadIdx.x, lane = tid & 63, wv = tid >> 6;
    int g = lane >> 4, t = lane & 15;
    int b = blockIdx.x >> 6, qb = blockIdx.x & 63;
    int s0 = qb << 6;

    const u16* Qb = Qt + ((long)b << 19);
    const u16* Kb = Kt + ((long)b << 19);
    const u16* Vb = Vv + ((long)b << 19);

    // Q B-frags for 4 qsets, register-resident
    bf16x8 qf[4][4];
    #pragma unroll
    for (int qs = 0; qs < 4; ++qs)
        #pragma unroll
        for (int ks = 0; ks < 4; ++ks)
            qf[qs][ks] = *(const bf16x8*)&Qb[(long)(s0 + qs * 16 + t) * 128 + ks * 32 + g * 8];

    f32x4 acco[4][8];   // [qset][c-subtile] partial O^T
    #pragma unroll
    for (int qs = 0; qs < 4; ++qs)
        #pragma unroll
        for (int i = 0; i < 8; ++i) acco[qs][i] = (f32x4){0.f, 0.f, 0.f, 0.f};
    float mm[4] = {-1e30f, -1e30f, -1e30f, -1e30f};
    float ll[4] = {0.f, 0.f, 0.f, 0.f};

    auto STAGE = [&](int buf, int kt) {
        int sk = kt << 6;
        #pragma unroll
        for (int i = 0; i < 4; ++i) {
            int seg = (wv << 2) + i;
            int lin = (seg << 6) + lane;
            {   // K: [64 s][16 ch16]; LDS slot ch holds source chunk ch^(s&7)
                int s = lin >> 4, ch = lin & 15;
                int gch = ch ^ (s & 7);
                gload16(Kb + (long)(sk + s) * 128 + (gch << 3), &ldsK[buf][seg * 512]);
            }
            {   // V: [128 c][8 ch16]; 8B-chunk ch8 holds source ch8^(c&14)
                int c = lin >> 3, ch = lin & 7;
                int gch = ch ^ ((c >> 1) & 7);
                gload16(Vb + ((long)c << 12) + sk + (gch << 3), &ldsV[buf][seg * 512]);
            }
        }
    };

    STAGE(0, 0);
    __syncthreads();
    int cur = 0;

    int sK = (wv << 4) + t;       // this wave's K row (key slice) in tile
    for (int kt = 0; kt < 64; ++kt) {
        if (kt < 63) STAGE(cur ^ 1, kt + 1);

        const u16* lK = ldsK[cur];
        const u16* lV = ldsV[cur];

        // K A-frags for this wave's 16 keys (reused across 4 qsets)
        bf16x8 kf[4];
        #pragma unroll
        for (int ks = 0; ks < 4; ++ks)
            kf[ks] = *(const bf16x8*)&lK[sK * 128 + ((((ks << 2) + g) ^ (sK & 7)) << 3)];

        // per qset: QK^T -> online partial softmax -> fp16 P frag
        f16x4 ppq[4];
        #pragma unroll
        for (int qs = 0; qs < 4; ++qs) {
            __builtin_amdgcn_s_setprio(1);
            f32x4 acc = (f32x4){0.f, 0.f, 0.f, 0.f};
            #pragma unroll
            for (int ks = 0; ks < 4; ++ks)
                acc = MFMA32(kf[ks], qf[qs][ks], acc);
            __builtin_amdgcn_s_setprio(0);
            float p0 = acc[0] * SC2, p1 = acc[1] * SC2;
            float p2 = acc[2] * SC2, p3 = acc[3] * SC2;

            float pmax = fmaxf(fmaxf(p0, p1), fmaxf(p2, p3));
            pmax = fmaxf(pmax, __shfl_xor(pmax, 16));
            pmax = fmaxf(pmax, __shfl_xor(pmax, 32));
            if (!__all(pmax - mm[qs] <= 12.0f)) {
                float mnew = fmaxf(mm[qs], pmax);
                float alpha = exp2f(mm[qs] - mnew);
                ll[qs] *= alpha;
                #pragma unroll
                for (int i = 0; i < 8; ++i) {
                    acco[qs][i][0] *= alpha; acco[qs][i][1] *= alpha;
                    acco[qs][i][2] *= alpha; acco[qs][i][3] *= alpha;
                }
                mm[qs] = mnew;
            }
            float e0 = exp2f(p0 - mm[qs]), e1 = exp2f(p1 - mm[qs]);
            float e2 = exp2f(p2 - mm[qs]), e3 = exp2f(p3 - mm[qs]);
            float ps = e0 + e1 + e2 + e3;
            ps += __shfl_xor(ps, 16);
            ps += __shfl_xor(ps, 32);
            ll[qs] += ps;
            f16x4 pp;
            pp[0] = (_Float16)e0; pp[1] = (_Float16)e1;
            pp[2] = (_Float16)e2; pp[3] = (_Float16)e3;
            ppq[qs] = pp;
        }

        // PV: acco[qs][ct] += V(c-rows, wave's s-slice) * P^T  (16x16x16 f16)
        __builtin_amdgcn_s_setprio(1);
        #pragma unroll
        for (int ct = 0; ct < 8; ++ct) {
            int c = (ct << 4) + t;
            f16x4 vf = *(const f16x4*)&lV[c * 64 + ((((wv << 2) + g) ^ (c & 14)) << 2)];
            #pragma unroll
            for (int qs = 0; qs < 4; ++qs)
                acco[qs][ct] = MFMA16(vf, ppq[qs], acco[qs][ct]);
        }
        __builtin_amdgcn_s_setprio(0);

        __syncthreads();
        cur ^= 1;
    }

    // ================= merge epilogue =================
    // 1) exchange per-wave (m,l) via LDS, compute final scale per qset
    float* mlsp = (float*)&ldsK[0][0];   // [wave][{m(64)|l(64)}]
    if (g == 0) {
        #pragma unroll
        for (int qs = 0; qs < 4; ++qs) {
            mlsp[(wv << 7) + (qs << 4) + t] = mm[qs];
            mlsp[(wv << 7) + 64 + (qs << 4) + t] = ll[qs];
        }
    }
    __syncthreads();
    float sc[4];
    #pragma unroll
    for (int qs = 0; qs < 4; ++qs) {
        int q = (qs << 4) + t;
        float m0 = mlsp[q],       l0 = mlsp[64 + q];
        float m1 = mlsp[128 + q], l1 = mlsp[192 + q];
        float m2 = mlsp[256 + q], l2 = mlsp[320 + q];
        float m3 = mlsp[384 + q], l3 = mlsp[448 + q];
        float mf = fmaxf(fmaxf(m0, m1), fmaxf(m2, m3));
        float lf = l0 * exp2f(m0 - mf) + l1 * exp2f(m1 - mf)
                 + l2 * exp2f(m2 - mf) + l3 * exp2f(m3 - mf);
        sc[qs] = exp2f(mm[qs] - mf) / lf;
    }
    __syncthreads();

    // 2) two-chunk scaled O-sum through LDS, fused with out = x * a
    float* base0 = (float*)&ldsK[0][0];   // waves 0,1 region (2 x 16 KB)
    float* base1 = (float*)&ldsV[0][0];   // waves 2,3 region
    float* myO = ((wv < 2) ? base0 : base1) + ((wv & 1) << 12);
    const float* xb = x + ((long)b << 19);
    float* ob = out + ((long)b << 19);

    #pragma unroll
    for (int half = 0; half < 2; ++half) {
        #pragma unroll
        for (int qs = 0; qs < 4; ++qs)
            #pragma unroll
            for (int ct4 = 0; ct4 < 4; ++ct4) {
                int ct = (half << 2) + ct4;
                #pragma unroll
                for (int r = 0; r < 4; ++r) {
                    int cl = (ct4 << 4) + (g << 2) + r;
                    myO[(cl << 6) + (qs << 4) + t] = acco[qs][ct][r] * sc[qs];
                }
            }
        __syncthreads();
        int q = tid & 63;
        int c0 = tid >> 6;
        #pragma unroll
        for (int i = 0; i < 16; ++i) {
            int cl = (i << 2) + c0;
            float sum = base0[(cl << 6) + q] + base0[4096 + (cl << 6) + q]
                      + base1[(cl << 6) + q] + base1[4096 + (cl << 6) + q];
            long gi = (((long)((half << 6) + cl)) << 12) + s0 + q;
            ob[gi] = xb[gi] * sum;
        }
        if (half == 0) __syncthreads();
    }
}

// ============================================================
extern "C" void kernel_launch(void* const* d_in, const int* in_sizes, int n_in,
                              void* d_out, int out_size, void* d_ws, size_t ws_size,
                              hipStream_t stream)
{
    const float* x    = (const float*)d_in[0];
    const float* gw   = (const float*)d_in[1];
    const float* gb   = (const float*)d_in[2];
    const float* w    = (const float*)d_in[3];
    const float* bias = (const float*)d_in[4];
    float* out = (float*)d_out;

    u16* hn  = (u16*)d_ws;                        // [8][4096][128] bf16 = 8 MB
    u16* Qt  = hn + (size_t)8 * 4096 * 128;       // [8][4096][128] bf16 = 8 MB
    u16* Kt  = Qt + (size_t)8 * 4096 * 128;       // [8][4096][128] bf16 = 8 MB
    u16* Vv  = Kt + (size_t)8 * 4096 * 128;       // [8][128][4096] fp16 = 8 MB
    u16* wbf = Vv + (size_t)8 * 128 * 4096;       // [384][128] bf16 = 96 KB
    float* gp = (float*)(wbf + (size_t)384 * 128); // [8][128]
    float* bp = gp + 1024;                         // [8][128]

    stats_kernel<<<256, 256, 0, stream>>>(x, gw, gb, gp, bp);
    wconv_kernel<<<48, 256, 0, stream>>>(w, wbf);
    apply_kernel<<<256, 256, 0, stream>>>(x, gp, bp, hn);
    qkvm_kernel<<<512, 256, 0, stream>>>(hn, wbf, bias, Qt, Kt, Vv);
    attn_kernel<<<512, 256, 0, stream>>>(Qt, Kt, Vv, x, out);
}